// Round 7
// baseline (108.328 us; speedup 1.0000x reference)
//
#include <hip/hip_runtime.h>
#include <hip/hip_bf16.h>
#include <math.h>

#define HID    128
#define BATCH  8192
#define NM     16
#define NROWS  (BATCH * NM)      // 131072
#define BN_EPS 1e-5f

#define S1_BLOCKS   256
#define S1_ROWS     (NROWS / S1_BLOCKS)   // 512
#define PREP_BLOCKS 32

// workspace layout (floats)
#define WS_PS    0
#define WS_PQ    (S1_BLOCKS * HID)          // 32768
#define WS_SCALE (2 * S1_BLOCKS * HID)      // 65536
#define WS_SHIFT (WS_SCALE + HID)           // 65664
#define WS_BW    (WS_SHIFT + HID)           // 65792 floats -> bf16 weight region
// bf16 region (ushort):
//   [0     :16384)  Wa1T rows 0..127   (c*128+k)
//   [16384 :32768)  Wa2T               (c*128+k)
//   [32768 :65536)  Wa1T rows 128..383 (c*256+k)
//   [65536 :81920)  Wc1T               (c*128+k)
//   [81920 :98304)  Wc2T               (c*128+k)
//   [98304 :102400) W1pack: (W1*scale) split hi/lo, K=32-packed per col
//                   k0..5=hi, k8..13=hi, k16..21=lo, rest 0   (col*32+k)

// output layout (floats)
#define O1 ((size_t)BATCH * NM)                 // h_pooled
#define O2 (O1 + (size_t)BATCH * HID)           // machine_v

#define G    4
#define ROWS (G * NM)   // 64 rows per main block
#define LDH  136        // padded bf16 row stride (272 B == 4 mod 32 banks)
#define ZLD  264        // z tile row stride
#define LDV  132        // critic tile row stride

typedef __attribute__((ext_vector_type(8))) short short8_t;
typedef __attribute__((ext_vector_type(4))) float f32x4;

#define MFMA16(a, b, c) __builtin_amdgcn_mfma_f32_16x16x32_bf16(a, b, c, 0, 0, 0)

__device__ __forceinline__ unsigned short f2bf(float x) {
    __hip_bfloat16 h = __float2bfloat16(x);
    return *reinterpret_cast<unsigned short*>(&h);
}
__device__ __forceinline__ float bf2f(unsigned short u) {
    __hip_bfloat16 h = *reinterpret_cast<__hip_bfloat16*>(&u);
    return __bfloat162float(h);
}
__device__ __forceinline__ float ftanh(float x) {
    float e = __expf(2.0f * x);
    return 1.0f - 2.0f / (e + 1.0f);
}

// ---------------------------------------------------------------------------
// Kernel 1: fused BN-stats (blocks 0..255, 512 thr) + weight prep (blocks 256+)
// ---------------------------------------------------------------------------
__global__ __launch_bounds__(512) void stats_prep_kernel(
    const float* __restrict__ fea1, const float* __restrict__ W1,
    const float* __restrict__ Wa1, const float* __restrict__ Wa2,
    const float* __restrict__ Wc1, const float* __restrict__ Wc2,
    float* __restrict__ ws, unsigned short* __restrict__ wbt)
{
    const int tid = threadIdx.x;
    const int blk = blockIdx.x;

    if (blk >= S1_BLOCKS) {
        // ---- prep: transposed bf16 weight layouts ----
        const int idx = (blk - S1_BLOCKS) * 512 + tid;   // 0..16383
        const int c = idx >> 7, k = idx & 127;
        wbt[c * 128 + k]         = f2bf(Wa1[(size_t)k * HID + c]);   // rows 0..127
        wbt[16384 + c * 128 + k] = f2bf(Wa2[(size_t)k * HID + c]);
        wbt[65536 + c * 128 + k] = f2bf(Wc1[(size_t)k * HID + c]);
        wbt[81920 + c * 128 + k] = f2bf(Wc2[(size_t)k * HID + c]);
        #pragma unroll
        for (int j = 0; j < 2; ++j) {
            const int i2 = idx + j * 16384;
            const int c2 = i2 >> 8, k2 = i2 & 255;
            wbt[32768 + c2 * 256 + k2] = f2bf(Wa1[(size_t)(HID + k2) * HID + c2]);
        }
        return;
    }

    // ---- stats: partial sums/sumsq of m_fea1 = fea1 @ W1 ----
    __shared__ float feaS[S1_ROWS * 6];
    __shared__ float w1S[6 * HID];
    __shared__ float redS[1024];

    const float* src = fea1 + (size_t)blk * (S1_ROWS * 6);
    for (int i = tid; i < S1_ROWS * 6; i += 512) feaS[i] = src[i];
    for (int i = tid; i < 6 * HID; i += 512)     w1S[i]  = W1[i];
    __syncthreads();

    const int c = tid & 127;
    const int h = tid >> 7;          // 0..3
    const float w0 = w1S[0 * HID + c], w1 = w1S[1 * HID + c], w2 = w1S[2 * HID + c];
    const float w3 = w1S[3 * HID + c], w4 = w1S[4 * HID + c], w5 = w1S[5 * HID + c];

    float s = 0.f, q = 0.f;
    const int rbeg = h * (S1_ROWS / 4);
    for (int r = rbeg; r < rbeg + S1_ROWS / 4; ++r) {
        const float* fr = feaS + r * 6;
        float m = fr[0] * w0 + fr[1] * w1 + fr[2] * w2
                + fr[3] * w3 + fr[4] * w4 + fr[5] * w5;
        s += m;
        q += m * m;
    }
    redS[tid] = s;
    redS[512 + tid] = q;
    __syncthreads();
    if (tid < 128) {
        ws[WS_PS + blk * HID + tid] = redS[tid] + redS[tid + 128] + redS[tid + 256] + redS[tid + 384];
        ws[WS_PQ + blk * HID + tid] = redS[512 + tid] + redS[512 + tid + 128]
                                    + redS[512 + tid + 256] + redS[512 + tid + 384];
    }
}

// ---------------------------------------------------------------------------
// Kernel 2: reduce partials -> scale/shift; build W1pack (scaled, hi/lo split)
// ---------------------------------------------------------------------------
__global__ __launch_bounds__(512) void bn_finalize_kernel(
    const float* __restrict__ gamma, const float* __restrict__ beta,
    const float* __restrict__ W1,
    float* __restrict__ ws, unsigned short* __restrict__ wbt)
{
    __shared__ float red[1024];
    __shared__ float scF[HID];
    const int tid = threadIdx.x;
    const int c  = tid & 127;
    const int pc = tid >> 7;

    float s = 0.f, q = 0.f;
    for (int p = pc * 64; p < pc * 64 + 64; ++p) {
        s += ws[WS_PS + p * HID + c];
        q += ws[WS_PQ + p * HID + c];
    }
    red[tid] = s;
    red[512 + tid] = q;
    __syncthreads();
    if (tid < 128) {
        float ss = red[tid] + red[tid + 128] + red[tid + 256] + red[tid + 384];
        float qq = red[512 + tid] + red[512 + tid + 128] + red[512 + tid + 256] + red[512 + tid + 384];
        const float inv = 1.0f / (float)NROWS;
        float mu  = ss * inv;
        float var = qq * inv - mu * mu;
        float sc  = gamma[tid] * rsqrtf(var + BN_EPS);
        ws[WS_SCALE + tid] = sc;
        ws[WS_SHIFT + tid] = beta[tid] - mu * sc;
        scF[tid] = sc;
    }
    __syncthreads();

    // W1pack: bn = fea @ (W1*scale) + shift; K=32 packing for one-MFMA split-fp32
    for (int idx = tid; idx < HID * 32; idx += 512) {
        const int col = idx >> 5, k = idx & 31;
        unsigned short v = 0;
        int kr = -1; bool lo = false;
        if (k < 6)                    kr = k;
        else if (k >= 8  && k < 14)   kr = k - 8;
        else if (k >= 16 && k < 22) { kr = k - 16; lo = true; }
        if (kr >= 0) {
            const float wv = W1[kr * HID + col] * scF[col];
            const unsigned short hi = f2bf(wv);
            v = lo ? f2bf(wv - bf2f(hi)) : hi;
        }
        wbt[98304 + col * 32 + k] = v;
    }
}

// ---------------------------------------------------------------------------
// Kernel 3: fused main kernel, N-split GEMMs. GEMM1/GEMM2 run TRANSPOSED
// (swapped MFMA args): C-fragment = 4 consecutive cols of one row -> packed
// ushort4 x1S writes, row-per-lane score reduce. Base-weight loads hoisted
// above the hm phase so their latency hides under hm compute.
// ---------------------------------------------------------------------------
__global__ __launch_bounds__(256, 4) void main_kernel(
    const float* __restrict__ fea1, const float* __restrict__ hpo,
    const unsigned char* __restrict__ mask,
    const float* __restrict__ ba1, const float* __restrict__ ba2,
    const float* __restrict__ Wa3, const float* __restrict__ ba3,
    const float* __restrict__ bc1, const float* __restrict__ bc2,
    const float* __restrict__ Wc3, const float* __restrict__ bc3,
    const float* __restrict__ ws, const unsigned short* __restrict__ wbt,
    float* __restrict__ out)
{
    __shared__ __align__(16) unsigned short hmS[ROWS * LDH];  // 17408 B
    __shared__ __align__(16) unsigned short x1S[ROWS * LDH];  // 17408 B (first 1536 B alias feaS)
    __shared__ __align__(16) unsigned short zS[G * ZLD];      // 2112 B
    __shared__ __align__(16) unsigned short v1bS[4 * LDV];    // 1056 B
    __shared__ __align__(16) unsigned short v2bS[4 * LDV];    // 1056 B
    __shared__ float scS[4 * ROWS];                           // 1024 B

    float* feaS = (float*)x1S;          // 384 floats (consumed before x1S written)

    const int tid = threadIdx.x;
    const int b0  = blockIdx.x * G;

    const int w    = tid >> 6;
    const int lane = tid & 63;
    const int lr   = lane & 15;
    const int lg   = lane >> 4;
    const int n0   = 2 * w;

    const unsigned short* wbt1  = wbt;
    const unsigned short* wbt2  = wbt + 16384;
    const unsigned short* wbtB  = wbt + 32768;
    const unsigned short* wbtC1 = wbt + 65536;
    const unsigned short* wbtC2 = wbt + 81920;
    const unsigned short* wbtW1 = wbt + 98304;

    // ---- stage ----
    for (int i = tid; i < ROWS * 6; i += 256) feaS[i] = fea1[(size_t)b0 * (NM * 6) + i];
    for (int i = tid; i < G * HID; i += 256) {
        const int g = i >> 7, cc = i & 127;
        zS[g * ZLD + 128 + cc] = f2bf(hpo[(size_t)b0 * HID + i]);
    }

    // prefetch: W1pack B-frags + GEMM1 B-frags (consumed after this barrier)
    short8_t bW[2];
    #pragma unroll
    for (int t = 0; t < 2; ++t)
        bW[t] = *(const short8_t*)(wbtW1 + ((n0 + t) * 16 + lr) * 32 + lg * 8);
    short8_t b1f[2][4];
    #pragma unroll
    for (int t = 0; t < 2; ++t) {
        const unsigned short* br = wbt1 + ((n0 + t) * 16 + lr) * 128 + lg * 8;
        #pragma unroll
        for (int kk = 0; kk < 4; ++kk) b1f[t][kk] = *(const short8_t*)(br + kk * 32);
    }
    const float sh0 = ws[WS_SHIFT + n0 * 16 + lr];
    const float sh1 = ws[WS_SHIFT + (n0 + 1) * 16 + lr];
    __syncthreads();

    // ---- hoisted base-GEMM weight loads: latency hides under hm compute ----
    short8_t bBf[2][8];
    #pragma unroll
    for (int t = 0; t < 2; ++t) {
        const unsigned short* br = wbtB + ((n0 + t) * 16 + lr) * 256 + lg * 8;
        #pragma unroll
        for (int kk = 0; kk < 8; ++kk) bBf[t][kk] = *(const short8_t*)(br + kk * 32);
    }

    // ---- hm = BN(fea @ W1) via ONE split-fp32 MFMA per (g,t) tile ----
    #pragma unroll
    for (int g = 0; g < 4; ++g) {
        const float* fr = feaS + (g * 16 + lr) * 6;
        short8_t af;
        #pragma unroll
        for (int j = 0; j < 6; ++j) {
            const float x = fr[j];
            const unsigned short hx = f2bf(x);
            const unsigned short lx = f2bf(x - bf2f(hx));
            unsigned short sel = (lg == 1) ? lx : hx;
            if (lg == 3) sel = 0;
            af[j] = (short)sel;
        }
        af[6] = 0; af[7] = 0;

        #pragma unroll
        for (int t = 0; t < 2; ++t) {
            const float sh = t ? sh1 : sh0;
            f32x4 acc = {sh, sh, sh, sh};
            acc = MFMA16(af, bW[t], acc);
            #pragma unroll
            for (int i = 0; i < 4; ++i)
                hmS[(g * 16 + lg * 4 + i) * LDH + (n0 + t) * 16 + lr] = f2bf(acc[i]);
            float hsum = acc[0] + acc[1] + acc[2] + acc[3];
            hsum += __shfl_xor(hsum, 16);
            hsum += __shfl_xor(hsum, 32);
            hsum *= (1.0f / NM);
            if (lg == 0) {
                out[O1 + (size_t)(b0 + g) * HID + (n0 + t) * 16 + lr] = hsum;
                zS[g * ZLD + (n0 + t) * 16 + lr] = f2bf(hsum);
            }
        }
    }
    __syncthreads();

    // =================== Phase A: base (regs) + critic L1 + GEMM1^T ========
    f32x4 accB[2];
    {
        short8_t za[8];
        const unsigned short* zr = zS + (lr & 3) * ZLD + lg * 8;
        #pragma unroll
        for (int kk = 0; kk < 8; ++kk) za[kk] = *(const short8_t*)(zr + kk * 32);

        // base = ba1 + z @ Wa1[128:384]; acc[i] = base[g=i][col (n0+t)*16+lr]
        #pragma unroll
        for (int t = 0; t < 2; ++t) {
            const float bi = ba1[(n0 + t) * 16 + lr];
            f32x4 acc = {bi, bi, bi, bi};
            #pragma unroll
            for (int kk = 0; kk < 8; ++kk)
                acc = MFMA16(za[kk], bBf[t][kk], acc);
            accB[t] = acc;
        }

        // critic L1 = tanh(hp @ Wc1 + bc1) -> v1bS (rows i = g)
        #pragma unroll
        for (int t = 0; t < 2; ++t) {
            const int n = n0 + t;
            const unsigned short* br = wbtC1 + (n * 16 + lr) * 128 + lg * 8;
            const float bi = bc1[n * 16 + lr];
            f32x4 acc = {bi, bi, bi, bi};
            acc = MFMA16(za[0], *(const short8_t*)(br),      acc);
            acc = MFMA16(za[1], *(const short8_t*)(br + 32), acc);
            acc = MFMA16(za[2], *(const short8_t*)(br + 64), acc);
            acc = MFMA16(za[3], *(const short8_t*)(br + 96), acc);
            if (lg == 0) {
                #pragma unroll
                for (int i = 0; i < 4; ++i)
                    v1bS[i * LDV + n * 16 + lr] = f2bf(ftanh(acc[i]));
            }
        }
    }

    // prefetch GEMM2 B fragments
    short8_t b2f[2][4];
    #pragma unroll
    for (int t = 0; t < 2; ++t) {
        const unsigned short* br = wbt2 + ((n0 + t) * 16 + lr) * 128 + lg * 8;
        #pragma unroll
        for (int kk = 0; kk < 4; ++kk) b2f[t][kk] = *(const short8_t*)(br + kk * 32);
    }

    // GEMM1^T (n-split): x1 = tanh(hm @ Wa1[0:128] + base), computed as
    // x1^T = Wa1^T @ hm^T (swapped args, same fragments). Lane holds
    // x1[row g*16+lr][cols (n0+t)*16 + lg*4 .. +3] -> packed ushort4 write.
    const int sb = (lane & 48) + ((lane >> 2) & 12);   // src lane base: lg*16 + lg*4
    #pragma unroll
    for (int g = 0; g < 4; ++g) {
        short8_t ha[4];
        const unsigned short* ar = hmS + (g * 16 + lr) * LDH + lg * 8;
        #pragma unroll
        for (int kk = 0; kk < 4; ++kk) ha[kk] = *(const short8_t*)(ar + kk * 32);
        #pragma unroll
        for (int t = 0; t < 2; ++t) {
            f32x4 acc;
            #pragma unroll
            for (int i = 0; i < 4; ++i)
                acc[i] = __shfl(accB[t][g], sb + i);   // base[g][(n0+t)*16+lg*4+i]
            acc = MFMA16(b1f[t][0], ha[0], acc);
            acc = MFMA16(b1f[t][1], ha[1], acc);
            acc = MFMA16(b1f[t][2], ha[2], acc);
            acc = MFMA16(b1f[t][3], ha[3], acc);
            ushort4 u4;
            u4.x = f2bf(ftanh(acc[0]));
            u4.y = f2bf(ftanh(acc[1]));
            u4.z = f2bf(ftanh(acc[2]));
            u4.w = f2bf(ftanh(acc[3]));
            *(ushort4*)&x1S[(g * 16 + lr) * LDH + (n0 + t) * 16 + lg * 4] = u4;
        }
    }
    __syncthreads();

    // =================== Phase B: critic L2 + GEMM2^T + score partials =====
    {
        // critic L2 = tanh(v1 @ Wc2 + bc2) -> v2bS
        short8_t va[4];
        const unsigned short* vr = v1bS + (lr & 3) * LDV + lg * 8;
        #pragma unroll
        for (int kk = 0; kk < 4; ++kk) va[kk] = *(const short8_t*)(vr + kk * 32);
        #pragma unroll
        for (int t = 0; t < 2; ++t) {
            const int n = n0 + t;
            const unsigned short* br = wbtC2 + (n * 16 + lr) * 128 + lg * 8;
            const float bi = bc2[n * 16 + lr];
            f32x4 acc = {bi, bi, bi, bi};
            acc = MFMA16(va[0], *(const short8_t*)(br),      acc);
            acc = MFMA16(va[1], *(const short8_t*)(br + 32), acc);
            acc = MFMA16(va[2], *(const short8_t*)(br + 64), acc);
            acc = MFMA16(va[3], *(const short8_t*)(br + 96), acc);
            if (lg == 0) {
                #pragma unroll
                for (int i = 0; i < 4; ++i)
                    v2bS[i * LDV + n * 16 + lr] = f2bf(ftanh(acc[i]));
            }
        }

        // GEMM2^T (n-split): x2^T = Wa2^T @ x1^T; lane holds x2[row g*16+lr]
        // [cols (n0+t)*16+lg*4..+3]; row-per-lane score reduce (2 shfl).
        f32x4 bi4[2], wv4[2];
        #pragma unroll
        for (int t = 0; t < 2; ++t) {
            bi4[t] = *(const f32x4*)(ba2 + (n0 + t) * 16 + lg * 4);
            wv4[t] = *(const f32x4*)(Wa3 + (n0 + t) * 16 + lg * 4);
        }
        #pragma unroll
        for (int g = 0; g < 4; ++g) {
            short8_t ha[4];
            const unsigned short* ar = x1S + (g * 16 + lr) * LDH + lg * 8;
            #pragma unroll
            for (int kk = 0; kk < 4; ++kk) ha[kk] = *(const short8_t*)(ar + kk * 32);
            float local = 0.f;
            #pragma unroll
            for (int t = 0; t < 2; ++t) {
                f32x4 acc = bi4[t];
                acc = MFMA16(b2f[t][0], ha[0], acc);
                acc = MFMA16(b2f[t][1], ha[1], acc);
                acc = MFMA16(b2f[t][2], ha[2], acc);
                acc = MFMA16(b2f[t][3], ha[3], acc);
                #pragma unroll
                for (int i = 0; i < 4; ++i)
                    local += ftanh(acc[i]) * wv4[t][i];
            }
            local += __shfl_xor(local, 16);
            local += __shfl_xor(local, 32);
            if (lg == 0) scS[w * ROWS + g * 16 + lr] = local;
        }
    }
    __syncthreads();

    // ---- softmax (wave w handles g=w; 16-lane parallel) ----
    {
        const int g = w;
        float s = scS[0 * ROWS + g * 16 + lr] + scS[1 * ROWS + g * 16 + lr]
                + scS[2 * ROWS + g * 16 + lr] + scS[3 * ROWS + g * 16 + lr];
        s = (s + ba3[0]) * 10.0f;
        if (mask[(size_t)(b0 + g) * NM + lr]) s = -INFINITY;
        float mx = s;
        mx = fmaxf(mx, __shfl_xor(mx, 1));
        mx = fmaxf(mx, __shfl_xor(mx, 2));
        mx = fmaxf(mx, __shfl_xor(mx, 4));
        mx = fmaxf(mx, __shfl_xor(mx, 8));
        float e = __expf(s - mx);
        float sum = e;
        sum += __shfl_xor(sum, 1);
        sum += __shfl_xor(sum, 2);
        sum += __shfl_xor(sum, 4);
        sum += __shfl_xor(sum, 8);
        if (lane < NM)
            out[(size_t)(b0 + g) * NM + lr] = e / sum;
    }

    // ---- machine_v (wave w handles g=w; 64-lane parallel over K) ----
    {
        const int g = w;
        const int k2 = lane * 2;
        float v0 = bf2f(v2bS[g * LDV + k2]);
        float v1 = bf2f(v2bS[g * LDV + k2 + 1]);
        float4 wc = *(const float4*)(Wc3 + k2 * 2);
        float p0 = v0 * wc.x + v1 * wc.z;
        float p1 = v0 * wc.y + v1 * wc.w;
        p0 += __shfl_xor(p0, 1);  p1 += __shfl_xor(p1, 1);
        p0 += __shfl_xor(p0, 2);  p1 += __shfl_xor(p1, 2);
        p0 += __shfl_xor(p0, 4);  p1 += __shfl_xor(p1, 4);
        p0 += __shfl_xor(p0, 8);  p1 += __shfl_xor(p1, 8);
        p0 += __shfl_xor(p0, 16); p1 += __shfl_xor(p1, 16);
        p0 += __shfl_xor(p0, 32); p1 += __shfl_xor(p1, 32);
        if (lane == 0) {
            out[O2 + (size_t)(b0 + g) * 2 + 0] = p0 + bc3[0];
            out[O2 + (size_t)(b0 + g) * 2 + 1] = p1 + bc3[1];
        }
    }
}

// ---------------------------------------------------------------------------
extern "C" void kernel_launch(void* const* d_in, const int* in_sizes, int n_in,
                              void* d_out, int out_size, void* d_ws, size_t ws_size,
                              hipStream_t stream)
{
    const float* fea1  = (const float*)d_in[0];
    const float* hpo   = (const float*)d_in[2];
    const unsigned char* mask = (const unsigned char*)d_in[3];
    const float* W1    = (const float*)d_in[4];
    const float* gamma = (const float*)d_in[8];
    const float* beta  = (const float*)d_in[9];
    const float* Wa1   = (const float*)d_in[10];
    const float* ba1   = (const float*)d_in[11];
    const float* Wa2   = (const float*)d_in[12];
    const float* ba2   = (const float*)d_in[13];
    const float* Wa3   = (const float*)d_in[14];
    const float* ba3   = (const float*)d_in[15];
    const float* Wc1   = (const float*)d_in[16];
    const float* bc1   = (const float*)d_in[17];
    const float* Wc2   = (const float*)d_in[18];
    const float* bc2   = (const float*)d_in[19];
    const float* Wc3   = (const float*)d_in[20];
    const float* bc3   = (const float*)d_in[21];

    float* ws = (float*)d_ws;
    unsigned short* wbt = (unsigned short*)(ws + WS_BW);
    float* out = (float*)d_out;

    stats_prep_kernel<<<S1_BLOCKS + PREP_BLOCKS, 512, 0, stream>>>(
        fea1, W1, Wa1, Wa2, Wc1, Wc2, ws, wbt);
    bn_finalize_kernel<<<1, 512, 0, stream>>>(gamma, beta, W1, ws, wbt);
    main_kernel<<<BATCH / G, 256, 0, stream>>>(
        fea1, hpo, mask, ba1, ba2, Wa3, ba3,
        bc1, bc2, Wc3, bc3, ws, wbt, out);
}

// Round 8
// 92.352 us; speedup vs baseline: 1.1730x; 1.1730x over previous
//
#include <hip/hip_runtime.h>
#include <hip/hip_bf16.h>
#include <math.h>

#define HID    128
#define BATCH  8192
#define NM     16
#define NROWS  (BATCH * NM)      // 131072
#define BN_EPS 1e-5f

#define S1_BLOCKS   256
#define S1_ROWS     (NROWS / S1_BLOCKS)   // 512
#define PREP_BLOCKS 32

// workspace layout (floats)
#define WS_PS    0
#define WS_PQ    (S1_BLOCKS * HID)          // 32768
#define WS_SCALE (2 * S1_BLOCKS * HID)      // 65536
#define WS_SHIFT (WS_SCALE + HID)           // 65664
#define WS_M1    (WS_SHIFT + HID)           // 65792: M1 = (W1*scale)@Wa1[128:256]  (6x128)
#define WS_SV    (WS_M1 + 6 * HID)          // 66560: shvec = shift@Wa1[128:256]
#define WS_N1    (WS_SV + HID)              // 66688: N1 = (W1*scale)@Wc1  (6x128)
#define WS_CV    (WS_N1 + 6 * HID)          // 67456: cvec = shift@Wc1 + bc1
#define WS_BW    (WS_CV + HID)              // 67584 floats -> bf16 weight region
// bf16 region (ushort):
//   [0     :16384) Wa1T rows 0..127    (c*128+k)   GEMM1
//   [16384 :32768) Wa2T                (c*128+k)   GEMM2
//   [32768 :49152) Wa1T rows 256..383  (c*128+k)   base (hpo part)
//   [49152 :65536) Wc2T                (c*128+k)   critic L2
//   [65536 :69632) W1pack: (W1*scale) hi/lo K=32-packed per col (col*32+k)

// output layout (floats)
#define O1 ((size_t)BATCH * NM)                 // h_pooled
#define O2 (O1 + (size_t)BATCH * HID)           // machine_v

#define G    4
#define ROWS (G * NM)   // 64 rows per main block
#define LDH  136        // padded bf16 row stride
#define ZLD  136        // hpo tile row stride
#define LDV  132        // critic tile row stride

typedef __attribute__((ext_vector_type(8))) short short8_t;
typedef __attribute__((ext_vector_type(4))) float f32x4;

#define MFMA16(a, b, c) __builtin_amdgcn_mfma_f32_16x16x32_bf16(a, b, c, 0, 0, 0)

__device__ __forceinline__ unsigned short f2bf(float x) {
    __hip_bfloat16 h = __float2bfloat16(x);
    return *reinterpret_cast<unsigned short*>(&h);
}
__device__ __forceinline__ float bf2f(unsigned short u) {
    __hip_bfloat16 h = *reinterpret_cast<__hip_bfloat16*>(&u);
    return __bfloat162float(h);
}
__device__ __forceinline__ float ftanh(float x) {
    float e = __expf(2.0f * x);
    return 1.0f - 2.0f / (e + 1.0f);
}

// ---------------------------------------------------------------------------
// Kernel 1: fused BN-stats (blocks 0..255) + weight prep (blocks 256+)
// ---------------------------------------------------------------------------
__global__ __launch_bounds__(512) void stats_prep_kernel(
    const float* __restrict__ fea1, const float* __restrict__ W1,
    const float* __restrict__ Wa1, const float* __restrict__ Wa2,
    const float* __restrict__ Wc2,
    float* __restrict__ ws, unsigned short* __restrict__ wbt)
{
    const int tid = threadIdx.x;
    const int blk = blockIdx.x;

    if (blk >= S1_BLOCKS) {
        const int idx = (blk - S1_BLOCKS) * 512 + tid;   // 0..16383
        const int c = idx >> 7, k = idx & 127;
        wbt[c * 128 + k]         = f2bf(Wa1[(size_t)k * HID + c]);         // rows 0..127
        wbt[16384 + c * 128 + k] = f2bf(Wa2[(size_t)k * HID + c]);
        wbt[32768 + c * 128 + k] = f2bf(Wa1[(size_t)(256 + k) * HID + c]); // hpo part
        wbt[49152 + c * 128 + k] = f2bf(Wc2[(size_t)k * HID + c]);
        return;
    }

    // ---- stats: partial sums/sumsq of m_fea1 = fea1 @ W1 ----
    __shared__ float feaS[S1_ROWS * 6];
    __shared__ float w1S[6 * HID];
    __shared__ float redS[1024];

    const float* src = fea1 + (size_t)blk * (S1_ROWS * 6);
    for (int i = tid; i < S1_ROWS * 6; i += 512) feaS[i] = src[i];
    for (int i = tid; i < 6 * HID; i += 512)     w1S[i]  = W1[i];
    __syncthreads();

    const int c = tid & 127;
    const int h = tid >> 7;          // 0..3
    const float w0 = w1S[0 * HID + c], w1 = w1S[1 * HID + c], w2 = w1S[2 * HID + c];
    const float w3 = w1S[3 * HID + c], w4 = w1S[4 * HID + c], w5 = w1S[5 * HID + c];

    float s = 0.f, q = 0.f;
    const int rbeg = h * (S1_ROWS / 4);
    for (int r = rbeg; r < rbeg + S1_ROWS / 4; ++r) {
        const float* fr = feaS + r * 6;
        float m = fr[0] * w0 + fr[1] * w1 + fr[2] * w2
                + fr[3] * w3 + fr[4] * w4 + fr[5] * w5;
        s += m;
        q += m * m;
    }
    redS[tid] = s;
    redS[512 + tid] = q;
    __syncthreads();
    if (tid < 128) {
        ws[WS_PS + blk * HID + tid] = redS[tid] + redS[tid + 128] + redS[tid + 256] + redS[tid + 384];
        ws[WS_PQ + blk * HID + tid] = redS[512 + tid] + redS[512 + tid + 128]
                                    + redS[512 + tid + 256] + redS[512 + tid + 384];
    }
}

// ---------------------------------------------------------------------------
// Kernel 2: scale/shift; M1/shvec/N1/cvec folds; W1pack
// ---------------------------------------------------------------------------
__global__ __launch_bounds__(512) void bn_finalize_kernel(
    const float* __restrict__ gamma, const float* __restrict__ beta,
    const float* __restrict__ W1,   const float* __restrict__ Wa1,
    const float* __restrict__ Wc1,  const float* __restrict__ bc1,
    float* __restrict__ ws, unsigned short* __restrict__ wbt)
{
    __shared__ float red[1024];
    __shared__ float scS2[HID], shS[HID];
    __shared__ float w1sS[6 * HID];   // W1 * scale
    const int tid = threadIdx.x;
    const int c  = tid & 127;
    const int pc = tid >> 7;

    float s = 0.f, q = 0.f;
    for (int p = pc * 64; p < pc * 64 + 64; ++p) {
        s += ws[WS_PS + p * HID + c];
        q += ws[WS_PQ + p * HID + c];
    }
    red[tid] = s;
    red[512 + tid] = q;
    __syncthreads();
    if (tid < 128) {
        float ss = red[tid] + red[tid + 128] + red[tid + 256] + red[tid + 384];
        float qq = red[512 + tid] + red[512 + tid + 128] + red[512 + tid + 256] + red[512 + tid + 384];
        const float inv = 1.0f / (float)NROWS;
        float mu  = ss * inv;
        float var = qq * inv - mu * mu;
        float sc  = gamma[tid] * rsqrtf(var + BN_EPS);
        ws[WS_SCALE + tid] = sc;
        ws[WS_SHIFT + tid] = beta[tid] - mu * sc;
        scS2[tid] = sc;
        shS[tid]  = beta[tid] - mu * sc;
    }
    __syncthreads();
    for (int i = tid; i < 6 * HID; i += 512)
        w1sS[i] = W1[i] * scS2[i & 127];
    __syncthreads();

    // 1792 K=128 dots: M1(768) | shvec(128) | N1(768) | cvec(128)
    for (int idx = tid; idx < 1792; idx += 512) {
        const int cc  = idx & 127;
        const int sel = idx >> 7;   // 0..13
        float acc = 0.f;
        if (sel < 6) {
            for (int k = 0; k < HID; ++k)
                acc += w1sS[sel * HID + k] * Wa1[(size_t)(128 + k) * HID + cc];
            ws[WS_M1 + sel * HID + cc] = acc;
        } else if (sel == 6) {
            for (int k = 0; k < HID; ++k)
                acc += shS[k] * Wa1[(size_t)(128 + k) * HID + cc];
            ws[WS_SV + cc] = acc;
        } else if (sel < 13) {
            const int j = sel - 7;
            for (int k = 0; k < HID; ++k)
                acc += w1sS[j * HID + k] * Wc1[(size_t)k * HID + cc];
            ws[WS_N1 + j * HID + cc] = acc;
        } else {
            for (int k = 0; k < HID; ++k)
                acc += shS[k] * Wc1[(size_t)k * HID + cc];
            ws[WS_CV + cc] = acc + bc1[cc];
        }
    }

    // W1pack: K=32 packing for one-MFMA split-fp32 (k0..5=hi, k8..13=hi, k16..21=lo)
    for (int idx = tid; idx < HID * 32; idx += 512) {
        const int col = idx >> 5, k = idx & 31;
        unsigned short v = 0;
        int kr = -1; bool lo = false;
        if (k < 6)                    kr = k;
        else if (k >= 8  && k < 14)   kr = k - 8;
        else if (k >= 16 && k < 22) { kr = k - 16; lo = true; }
        if (kr >= 0) {
            const float wv = w1sS[kr * HID + col];
            const unsigned short hi = f2bf(wv);
            v = lo ? f2bf(wv - bf2f(hi)) : hi;
        }
        wbt[65536 + col * 32 + k] = v;
    }
}

// ---------------------------------------------------------------------------
// Kernel 3: fused main kernel, N-split GEMMs. hp-dependent ops algebraically
// folded to rank-6 contractions (M1/N1/shvec/cvec): no zS[hp], base K=128,
// critic L1 on VALU, exact fp32 h_pooled.
// ---------------------------------------------------------------------------
__global__ __launch_bounds__(256, 4) void main_kernel(
    const float* __restrict__ fea1, const float* __restrict__ hpo,
    const unsigned char* __restrict__ mask,
    const float* __restrict__ W1,
    const float* __restrict__ ba1, const float* __restrict__ ba2,
    const float* __restrict__ Wa3, const float* __restrict__ ba3,
    const float* __restrict__ bc2,
    const float* __restrict__ Wc3, const float* __restrict__ bc3,
    const float* __restrict__ ws, const unsigned short* __restrict__ wbt,
    float* __restrict__ out)
{
    __shared__ __align__(16) unsigned short hmS[ROWS * LDH];  // 17408 B
    __shared__ __align__(16) unsigned short x1S[ROWS * LDH];  // 17408 B (first 1536 B alias feaS)
    __shared__ __align__(16) unsigned short zS[G * ZLD];      // 1088 B (hpo only)
    __shared__ __align__(16) unsigned short v1bS[4 * LDV];    // 1056 B
    __shared__ __align__(16) unsigned short v2bS[4 * LDV];    // 1056 B
    __shared__ float scS[4 * ROWS];                           // 1024 B
    __shared__ float fmS[4][8];                               // 128 B (fea row-means)

    float* feaS = (float*)x1S;          // 384 floats (dead before x1S written)

    const int tid = threadIdx.x;
    const int b0  = blockIdx.x * G;

    const int w    = tid >> 6;
    const int lane = tid & 63;
    const int lr   = lane & 15;
    const int lg   = lane >> 4;
    const int n0   = 2 * w;

    const unsigned short* wbt1  = wbt;
    const unsigned short* wbt2  = wbt + 16384;
    const unsigned short* wbtB  = wbt + 32768;
    const unsigned short* wbtC2 = wbt + 49152;
    const unsigned short* wbtW1 = wbt + 65536;

    // ---- stage ----
    for (int i = tid; i < ROWS * 6; i += 256) feaS[i] = fea1[(size_t)b0 * (NM * 6) + i];
    for (int i = tid; i < G * HID; i += 256) {
        const int g = i >> 7, cc = i & 127;
        zS[g * ZLD + cc] = f2bf(hpo[(size_t)b0 * HID + i]);
    }

    // prefetch (consumed right after barrier; short live ranges only)
    short8_t bW[2];
    #pragma unroll
    for (int t = 0; t < 2; ++t)
        bW[t] = *(const short8_t*)(wbtW1 + ((n0 + t) * 16 + lr) * 32 + lg * 8);
    short8_t b1f[2][4];
    #pragma unroll
    for (int t = 0; t < 2; ++t) {
        const unsigned short* br = wbt1 + ((n0 + t) * 16 + lr) * 128 + lg * 8;
        #pragma unroll
        for (int kk = 0; kk < 4; ++kk) b1f[t][kk] = *(const short8_t*)(br + kk * 32);
    }
    const float sh0 = ws[WS_SHIFT + n0 * 16 + lr];
    const float sh1 = ws[WS_SHIFT + (n0 + 1) * 16 + lr];
    __syncthreads();

    // ---- hm = BN(fea @ W1) via ONE split-fp32 MFMA per (g,t) tile ----
    #pragma unroll
    for (int g = 0; g < 4; ++g) {
        const float* fr = feaS + (g * 16 + lr) * 6;
        short8_t af;
        #pragma unroll
        for (int j = 0; j < 6; ++j) {
            const float x = fr[j];
            const unsigned short hx = f2bf(x);
            const unsigned short lx = f2bf(x - bf2f(hx));
            unsigned short sel = (lg == 1) ? lx : hx;
            if (lg == 3) sel = 0;
            af[j] = (short)sel;
        }
        af[6] = 0; af[7] = 0;

        #pragma unroll
        for (int t = 0; t < 2; ++t) {
            const float sh = t ? sh1 : sh0;
            f32x4 acc = {sh, sh, sh, sh};
            acc = MFMA16(af, bW[t], acc);
            #pragma unroll
            for (int i = 0; i < 4; ++i)
                hmS[(g * 16 + lg * 4 + i) * LDH + (n0 + t) * 16 + lr] = f2bf(acc[i]);
        }
    }
    // fea row-means (exact fp32), 24 threads
    if (tid < 24) {
        const int g = tid / 6, j = tid % 6;
        float s = 0.f;
        for (int m = 0; m < NM; ++m) s += feaS[(g * 16 + m) * 6 + j];
        fmS[g][j] = s * (1.0f / NM);
    }
    __syncthreads();

    // =================== Phase A: base + critic L1 + hp + GEMM1 ============
    f32x4 accB[2];
    {
        short8_t bBf[2][4];
        #pragma unroll
        for (int t = 0; t < 2; ++t) {
            const unsigned short* br = wbtB + ((n0 + t) * 16 + lr) * 128 + lg * 8;
            #pragma unroll
            for (int kk = 0; kk < 4; ++kk) bBf[t][kk] = *(const short8_t*)(br + kk * 32);
        }
        short8_t za[4];
        const unsigned short* zr = zS + (lr & 3) * ZLD + lg * 8;
        #pragma unroll
        for (int kk = 0; kk < 4; ++kk) za[kk] = *(const short8_t*)(zr + kk * 32);

        float fm[4][6];
        #pragma unroll
        for (int g = 0; g < 4; ++g)
            #pragma unroll
            for (int j = 0; j < 6; ++j) fm[g][j] = fmS[g][j];

        // base = ba1 + shvec + fea_mean@M1 (VALU) + hpo @ Wa1[256:384] (MFMA)
        #pragma unroll
        for (int t = 0; t < 2; ++t) {
            const int col = (n0 + t) * 16 + lr;
            const float bias = ba1[col] + ws[WS_SV + col];
            float b_[4];
            #pragma unroll
            for (int g = 0; g < 4; ++g) {
                float a = bias;
                #pragma unroll
                for (int j = 0; j < 6; ++j) a += fm[g][j] * ws[WS_M1 + j * HID + col];
                b_[g] = a;
            }
            f32x4 acc = {b_[0], b_[1], b_[2], b_[3]};
            acc = MFMA16(za[0], bBf[t][0], acc);
            acc = MFMA16(za[1], bBf[t][1], acc);
            acc = MFMA16(za[2], bBf[t][2], acc);
            acc = MFMA16(za[3], bBf[t][3], acc);
            accB[t] = acc;
        }

        // critic L1 (VALU, g = lg): v1 = tanh(fea_mean@N1 + cvec)
        #pragma unroll
        for (int t = 0; t < 2; ++t) {
            const int col = (n0 + t) * 16 + lr;
            float a = ws[WS_CV + col];
            #pragma unroll
            for (int j = 0; j < 6; ++j) a += fm[lg][j] * ws[WS_N1 + j * HID + col];
            v1bS[lg * LDV + col] = f2bf(ftanh(a));
        }

        // h_pooled output (exact fp32, g = lg)
        #pragma unroll
        for (int t = 0; t < 2; ++t) {
            const int col = (n0 + t) * 16 + lr;
            float a = 0.f;
            #pragma unroll
            for (int j = 0; j < 6; ++j) a += fm[lg][j] * W1[j * HID + col];
            a = a * ws[WS_SCALE + col] + ws[WS_SHIFT + col];
            out[O1 + (size_t)(b0 + lg) * HID + col] = a;
        }
    }

    // prefetch GEMM2 B fragments
    short8_t b2f[2][4];
    #pragma unroll
    for (int t = 0; t < 2; ++t) {
        const unsigned short* br = wbt2 + ((n0 + t) * 16 + lr) * 128 + lg * 8;
        #pragma unroll
        for (int kk = 0; kk < 4; ++kk) b2f[t][kk] = *(const short8_t*)(br + kk * 32);
    }

    // GEMM1 (n-split): x1 = tanh(hm @ Wa1[0:128] + base) -> x1S
    #pragma unroll
    for (int g = 0; g < 4; ++g) {
        short8_t ha[4];
        const unsigned short* ar = hmS + (g * 16 + lr) * LDH + lg * 8;
        #pragma unroll
        for (int kk = 0; kk < 4; ++kk) ha[kk] = *(const short8_t*)(ar + kk * 32);
        #pragma unroll
        for (int t = 0; t < 2; ++t) {
            const float bz = accB[t][g];
            f32x4 acc = {bz, bz, bz, bz};
            acc = MFMA16(ha[0], b1f[t][0], acc);
            acc = MFMA16(ha[1], b1f[t][1], acc);
            acc = MFMA16(ha[2], b1f[t][2], acc);
            acc = MFMA16(ha[3], b1f[t][3], acc);
            #pragma unroll
            for (int i = 0; i < 4; ++i)
                x1S[(g * 16 + lg * 4 + i) * LDH + (n0 + t) * 16 + lr] = f2bf(ftanh(acc[i]));
        }
    }
    __syncthreads();

    // =================== Phase B: critic L2 + GEMM2 + score partials =======
    {
        // critic L2 = tanh(v1 @ Wc2 + bc2) -> v2bS
        short8_t va[4];
        const unsigned short* vr = v1bS + (lr & 3) * LDV + lg * 8;
        #pragma unroll
        for (int kk = 0; kk < 4; ++kk) va[kk] = *(const short8_t*)(vr + kk * 32);
        #pragma unroll
        for (int t = 0; t < 2; ++t) {
            const int n = n0 + t;
            const unsigned short* br = wbtC2 + (n * 16 + lr) * 128 + lg * 8;
            const float bi = bc2[n * 16 + lr];
            f32x4 acc = {bi, bi, bi, bi};
            acc = MFMA16(va[0], *(const short8_t*)(br),      acc);
            acc = MFMA16(va[1], *(const short8_t*)(br + 32), acc);
            acc = MFMA16(va[2], *(const short8_t*)(br + 64), acc);
            acc = MFMA16(va[3], *(const short8_t*)(br + 96), acc);
            if (lg == 0) {
                #pragma unroll
                for (int i = 0; i < 4; ++i)
                    v2bS[i * LDV + n * 16 + lr] = f2bf(ftanh(acc[i]));
            }
        }

        // GEMM2 (n-split): x2 = tanh(x1 @ Wa2 + ba2); partial scores
        float p[4][4];
        #pragma unroll
        for (int g = 0; g < 4; ++g)
            #pragma unroll
            for (int i = 0; i < 4; ++i) p[g][i] = 0.f;

        const float wv0 = Wa3[n0 * 16 + lr];
        const float wv1 = Wa3[(n0 + 1) * 16 + lr];
        const float bi0 = ba2[n0 * 16 + lr];
        const float bi1 = ba2[(n0 + 1) * 16 + lr];
        #pragma unroll
        for (int g = 0; g < 4; ++g) {
            short8_t ha[4];
            const unsigned short* ar = x1S + (g * 16 + lr) * LDH + lg * 8;
            #pragma unroll
            for (int kk = 0; kk < 4; ++kk) ha[kk] = *(const short8_t*)(ar + kk * 32);
            #pragma unroll
            for (int t = 0; t < 2; ++t) {
                const float bi = t ? bi1 : bi0;
                f32x4 acc = {bi, bi, bi, bi};
                acc = MFMA16(ha[0], b2f[t][0], acc);
                acc = MFMA16(ha[1], b2f[t][1], acc);
                acc = MFMA16(ha[2], b2f[t][2], acc);
                acc = MFMA16(ha[3], b2f[t][3], acc);
                const float wv = t ? wv1 : wv0;
                #pragma unroll
                for (int i = 0; i < 4; ++i)
                    p[g][i] += ftanh(acc[i]) * wv;
            }
        }
        #pragma unroll
        for (int g = 0; g < 4; ++g) {
            #pragma unroll
            for (int i = 0; i < 4; ++i) {
                float v = p[g][i];
                v += __shfl_xor(v, 1);
                v += __shfl_xor(v, 2);
                v += __shfl_xor(v, 4);
                v += __shfl_xor(v, 8);
                if (lr == 0) scS[w * ROWS + g * 16 + lg * 4 + i] = v;
            }
        }
    }
    __syncthreads();

    // ---- softmax (wave w handles g=w; 16-lane parallel) ----
    {
        const int g = w;
        float s = scS[0 * ROWS + g * 16 + lr] + scS[1 * ROWS + g * 16 + lr]
                + scS[2 * ROWS + g * 16 + lr] + scS[3 * ROWS + g * 16 + lr];
        s = (s + ba3[0]) * 10.0f;
        if (mask[(size_t)(b0 + g) * NM + lr]) s = -INFINITY;
        float mx = s;
        mx = fmaxf(mx, __shfl_xor(mx, 1));
        mx = fmaxf(mx, __shfl_xor(mx, 2));
        mx = fmaxf(mx, __shfl_xor(mx, 4));
        mx = fmaxf(mx, __shfl_xor(mx, 8));
        float e = __expf(s - mx);
        float sum = e;
        sum += __shfl_xor(sum, 1);
        sum += __shfl_xor(sum, 2);
        sum += __shfl_xor(sum, 4);
        sum += __shfl_xor(sum, 8);
        if (lane < NM)
            out[(size_t)(b0 + g) * NM + lr] = e / sum;
    }

    // ---- machine_v (wave w handles g=w; 64-lane parallel over K) ----
    {
        const int g = w;
        const int k2 = lane * 2;
        float v0 = bf2f(v2bS[g * LDV + k2]);
        float v1 = bf2f(v2bS[g * LDV + k2 + 1]);
        float4 wc = *(const float4*)(Wc3 + k2 * 2);
        float p0 = v0 * wc.x + v1 * wc.z;
        float p1 = v0 * wc.y + v1 * wc.w;
        p0 += __shfl_xor(p0, 1);  p1 += __shfl_xor(p1, 1);
        p0 += __shfl_xor(p0, 2);  p1 += __shfl_xor(p1, 2);
        p0 += __shfl_xor(p0, 4);  p1 += __shfl_xor(p1, 4);
        p0 += __shfl_xor(p0, 8);  p1 += __shfl_xor(p1, 8);
        p0 += __shfl_xor(p0, 16); p1 += __shfl_xor(p1, 16);
        p0 += __shfl_xor(p0, 32); p1 += __shfl_xor(p1, 32);
        if (lane == 0) {
            out[O2 + (size_t)(b0 + g) * 2 + 0] = p0 + bc3[0];
            out[O2 + (size_t)(b0 + g) * 2 + 1] = p1 + bc3[1];
        }
    }
}

// ---------------------------------------------------------------------------
extern "C" void kernel_launch(void* const* d_in, const int* in_sizes, int n_in,
                              void* d_out, int out_size, void* d_ws, size_t ws_size,
                              hipStream_t stream)
{
    const float* fea1  = (const float*)d_in[0];
    const float* hpo   = (const float*)d_in[2];
    const unsigned char* mask = (const unsigned char*)d_in[3];
    const float* W1    = (const float*)d_in[4];
    const float* gamma = (const float*)d_in[8];
    const float* beta  = (const float*)d_in[9];
    const float* Wa1   = (const float*)d_in[10];
    const float* ba1   = (const float*)d_in[11];
    const float* Wa2   = (const float*)d_in[12];
    const float* ba2   = (const float*)d_in[13];
    const float* Wa3   = (const float*)d_in[14];
    const float* ba3   = (const float*)d_in[15];
    const float* Wc1   = (const float*)d_in[16];
    const float* bc1   = (const float*)d_in[17];
    const float* Wc2   = (const float*)d_in[18];
    const float* bc2   = (const float*)d_in[19];
    const float* Wc3   = (const float*)d_in[20];
    const float* bc3   = (const float*)d_in[21];

    float* ws = (float*)d_ws;
    unsigned short* wbt = (unsigned short*)(ws + WS_BW);
    float* out = (float*)d_out;

    stats_prep_kernel<<<S1_BLOCKS + PREP_BLOCKS, 512, 0, stream>>>(
        fea1, W1, Wa1, Wa2, Wc2, ws, wbt);
    bn_finalize_kernel<<<1, 512, 0, stream>>>(gamma, beta, W1, Wa1, Wc1, bc1, ws, wbt);
    main_kernel<<<BATCH / G, 256, 0, stream>>>(
        fea1, hpo, mask, W1, ba1, ba2, Wa3, ba3,
        bc2, Wc3, bc3, ws, wbt, out);
}